// Round 7
// baseline (708.860 us; speedup 1.0000x reference)
//
#include <hip/hip_runtime.h>
#include <stdint.h>

// CausalMultiHeadAttention — round 7.
// fp32 in memory; 16-bit MFMA compute.
//  - GEMM: m97-style staging via global_load_lds (16B), lane-linear LDS
//    block layout (blk*1KB + lane*16B) -> ds_read_b128 frag reads are
//    2-way-bank-aliased only (free). BK=32, 128x128 tile. bf16 pre-cvt.
//  - Attention: NO LDS, NO BARRIERS. K/V^T fragments loaded directly from
//    global (coalesced per the fragment layout); waves fully independent;
//    dense branch-free r3-style inner loop (no ktmax branches).
// ws fast path: xb | Wq..Wo_bf | Qw | Kw | Vtw ; O reuses xb (dead by then).

#define D_MODEL 1024
#define NHEAD   16
#define DK      64
#define BATCH   4
#define SEQ     2048
#define MTOT    (BATCH*SEQ)   // 8192

typedef unsigned short u16;
typedef unsigned int   u32;
typedef __bf16    bf16x8  __attribute__((ext_vector_type(8)));
typedef float     floatx4 __attribute__((ext_vector_type(4)));
typedef __fp16    fp16x2  __attribute__((ext_vector_type(2)));
typedef _Float16  half4_t __attribute__((ext_vector_type(4)));
typedef _Float16  half8_t __attribute__((ext_vector_type(8)));

// round-to-nearest-even f32 -> bf16
__device__ __forceinline__ u16 f2bf(float f){
  union { float f; u32 u; } c; c.f = f;
  u32 x = c.u;
  x += 0x7fffu + ((x >> 16) & 1u);
  return (u16)(x >> 16);
}
__device__ __forceinline__ u32 pkbf(float a, float b){   // RNE pack pair
  return ((u32)f2bf(b) << 16) | f2bf(a);
}
// f32 pair -> packed fp16 bits (RTZ, hardware packed cvt)
__device__ __forceinline__ u32 pkh(float a, float b){
  union { fp16x2 h; u32 u; } c; c.h = __builtin_amdgcn_cvt_pkrtz(a, b); return c.u;
}
// 8 fp32 -> 8 bf16 by truncation (one v_perm per pair) — fallback staging
__device__ __forceinline__ uint4 pk8(const float* __restrict__ p){
  uint4 a = *(const uint4*)p;
  uint4 b = *(const uint4*)(p + 4);
  uint4 r;
  r.x = __builtin_amdgcn_perm(a.y, a.x, 0x07060302);
  r.y = __builtin_amdgcn_perm(a.w, a.z, 0x07060302);
  r.z = __builtin_amdgcn_perm(b.y, b.x, 0x07060302);
  r.w = __builtin_amdgcn_perm(b.w, b.z, 0x07060302);
  return r;
}
// async global -> LDS, 16 B per lane; lds base must be wave-uniform,
// lane i lands at lds + i*16  [m97/m104 semantics]
__device__ __forceinline__ void async_ld16(const u16* g, u16* lds_base){
  __builtin_amdgcn_global_load_lds(
      (const __attribute__((address_space(1))) void*)g,
      (__attribute__((address_space(3))) void*)lds_base,
      16, 0, 0);
}

// ---------------------------------------------------------------------------
// fp32 -> bf16 conversion pass (x and 4 weight matrices), RNE.
// ---------------------------------------------------------------------------
__global__ __launch_bounds__(256, 8)
void cvt_bf16(const float* __restrict__ x,
              const float* __restrict__ w0, const float* __restrict__ w1,
              const float* __restrict__ w2, const float* __restrict__ w3,
              u16* __restrict__ xb, u16* __restrict__ wb0, u16* __restrict__ wb1,
              u16* __restrict__ wb2, u16* __restrict__ wb3)
{
  const int bx = blockIdx.x;
  const float* src; u16* dst; size_t off;
  if (bx < 4096) { src = x; dst = xb; off = (size_t)bx * 2048; }
  else {
    int i = bx - 4096; const int wi = i >> 9; i &= 511;
    src = wi == 0 ? w0 : wi == 1 ? w1 : wi == 2 ? w2 : w3;
    dst = wi == 0 ? wb0 : wi == 1 ? wb1 : wi == 2 ? wb2 : wb3;
    off = (size_t)i * 2048;
  }
  const int t = threadIdx.x;
  const float* p = src + off + t * 8;
  float4 a = *(const float4*)p;
  float4 b = *(const float4*)(p + 4);
  uint4 r;
  r.x = pkbf(a.x, a.y); r.y = pkbf(a.z, a.w);
  r.z = pkbf(b.x, b.y); r.w = pkbf(b.z, b.w);
  *(uint4*)(dst + off + t * 8) = r;
}

// ---------------------------------------------------------------------------
// GEMM: C[m,n] = (sum_k A[m,k]*W[n,k] + bias[n]) * scale.
// 128x128 tile, BK=32, 4 waves 2x2, each wave 64x64 = 4x4 MFMA.
// LDS layout (per matrix, 8KB): 8 blocks of [16 rows x 32 k]; block b holds
// rows b*16..b*16+15; within block, lane-linear: off(row16,kchunk) =
// b*1024B + kchunk*256B + row16*16B (== lane*16B for lane = kchunk*16+row16).
// Staging: ASYNC -> global_load_lds 16B (wave w stages blocks 2w,2w+1);
//          else  -> pk8(fp32) + ds_write (same layout).
// Frag read row R chunk q: u16 idx (R>>4)*512 + q*128 + (R&15)*8 ->
// ds_read_b128, banks (l15*4+d)%32 -> 2-way only (free).
// MODE 0: fp32 [m][N] | MODE 1: fp16 [bh][s][dk] | MODE 2: fp16 [bh][dk][s].
// ---------------------------------------------------------------------------
template<int MODE, int AASYNC, int WASYNC>
__global__ __launch_bounds__(256, 3)
void gemm_bt(const void* __restrict__ Av, const void* __restrict__ Wv,
             const float* __restrict__ bias, void* __restrict__ outv,
             float scale)
{
  __shared__ __align__(16) u16 As[128*32];
  __shared__ __align__(16) u16 Bs[128*32];

  const int t    = threadIdx.x;
  const int n0   = blockIdx.x * 128;
  const int m0   = blockIdx.y * 128;
  const int wid  = t >> 6, lane = t & 63;
  const int wr   = wid >> 1, wc = wid & 1;
  const int quad = lane >> 4, l15 = lane & 15;

  const u16*   Ab16 = (const u16*)Av;   const float* Af32 = (const float*)Av;
  const u16*   Wb16 = (const u16*)Wv;   const float* Wf32 = (const float*)Wv;

  // async staging: wave stages blocks 2*wid, 2*wid+1; lane -> row16=lane&15,
  // kchunk=lane>>4
  const int ab0 = 2*wid, ab1 = 2*wid + 1;
  const int arow0 = ab0*16 + l15, arow1 = ab1*16 + l15;
  const int acol  = quad * 8;

  // register staging (fallback): thread t covers chunks c = t, t+256
  const int c0 = t, c1 = t + 256;
  const int b0 = c0 >> 6, i0 = c0 & 63;
  const int b1 = c1 >> 6, i1 = c1 & 63;

  floatx4 acc[4][4] = {};

  for (int k0 = 0; k0 < D_MODEL; k0 += 32) {
    __syncthreads();
    if (AASYNC) {
      async_ld16(Ab16 + (size_t)(m0 + arow0)*D_MODEL + k0 + acol, &As[ab0*512]);
      async_ld16(Ab16 + (size_t)(m0 + arow1)*D_MODEL + k0 + acol, &As[ab1*512]);
    } else {
      *(uint4*)&As[b0*512 + i0*8] = pk8(Af32 + (size_t)(m0 + b0*16 + (i0&15))*D_MODEL + k0 + (i0>>4)*8);
      *(uint4*)&As[b1*512 + i1*8] = pk8(Af32 + (size_t)(m0 + b1*16 + (i1&15))*D_MODEL + k0 + (i1>>4)*8);
    }
    if (WASYNC) {
      async_ld16(Wb16 + (size_t)(n0 + arow0)*D_MODEL + k0 + acol, &Bs[ab0*512]);
      async_ld16(Wb16 + (size_t)(n0 + arow1)*D_MODEL + k0 + acol, &Bs[ab1*512]);
    } else {
      *(uint4*)&Bs[b0*512 + i0*8] = pk8(Wf32 + (size_t)(n0 + b0*16 + (i0&15))*D_MODEL + k0 + (i0>>4)*8);
      *(uint4*)&Bs[b1*512 + i1*8] = pk8(Wf32 + (size_t)(n0 + b1*16 + (i1&15))*D_MODEL + k0 + (i1>>4)*8);
    }
    __syncthreads();

    bf16x8 af[4], bf[4];
#pragma unroll
    for (int i = 0; i < 4; ++i) {
      af[i] = *(const bf16x8*)&As[(wr*4 + i)*512 + quad*128 + l15*8];
      bf[i] = *(const bf16x8*)&Bs[(wc*4 + i)*512 + quad*128 + l15*8];
    }
#pragma unroll
    for (int mi = 0; mi < 4; ++mi)
#pragma unroll
      for (int nj = 0; nj < 4; ++nj) {
        if (MODE == 2)
          acc[mi][nj] = __builtin_amdgcn_mfma_f32_16x16x32_bf16(af[mi], bf[nj], acc[mi][nj], 0, 0, 0);
        else
          acc[mi][nj] = __builtin_amdgcn_mfma_f32_16x16x32_bf16(bf[nj], af[mi], acc[mi][nj], 0, 0, 0);
      }
  }

  if (MODE != 2) {
    // lane = m, regs = n-consecutive
#pragma unroll
    for (int nj = 0; nj < 4; ++nj) {
      const int nb = n0 + wc*64 + nj*16 + quad*4;
      const float4 b4 = *(const float4*)(bias + nb);
#pragma unroll
      for (int mi = 0; mi < 4; ++mi) {
        const int m = m0 + wr*64 + mi*16 + l15;
        floatx4 d = acc[mi][nj];
        const float v0 = (d[0]+b4.x)*scale, v1 = (d[1]+b4.y)*scale;
        const float v2 = (d[2]+b4.z)*scale, v3 = (d[3]+b4.w)*scale;
        if (MODE == 0) {
          *(float4*)((float*)outv + (size_t)m*D_MODEL + nb) = make_float4(v0, v1, v2, v3);
        } else {
          const int b = m >> 11, s = m & 2047, h = nb >> 6, dd = nb & 63;
          u16* dst = (u16*)outv + ((((size_t)b*NHEAD + h)*SEQ + s) << 6) + dd;
          *(uint2*)dst = make_uint2(pkh(v0, v1), pkh(v2, v3));
        }
      }
    }
  } else {
    // lane = n (dd), regs = m (s)-consecutive
#pragma unroll
    for (int nj = 0; nj < 4; ++nj) {
      const int n  = n0 + wc*64 + nj*16 + l15;
      const float bvv = bias[n];
      const int h = n >> 6, dd = n & 63;
#pragma unroll
      for (int mi = 0; mi < 4; ++mi) {
        const int mb = m0 + wr*64 + mi*16 + quad*4;
        const int b = mb >> 11, s = mb & 2047;
        floatx4 d = acc[mi][nj];
        u16* dst = (u16*)outv + (((size_t)b*NHEAD + h)*DK + dd)*SEQ + s;
        *(uint2*)dst = make_uint2(pkh(d[0]+bvv, d[1]+bvv), pkh(d[2]+bvv, d[3]+bvv));
      }
    }
  }
}

// ---------------------------------------------------------------------------
// Barrier-free MFMA flash attention. Grid (SEQ/128 reversed, B*H), 4 waves,
// 32 queries/wave — waves fully independent, NO LDS, NO __syncthreads.
// K-fragments (16B/lane) and V^T-fragments (8B/lane) loaded directly from
// global; per tile 8 K-loads + 16 V-loads in flight. Dense branch-free
// 64-key tile loop (mask applied only to the diagonal-straddling tile).
//  phase1 S^T = K·Q^T (16x16x32 f16): C col=query=lane&15, row=key.
//  phase2 O^T = V^T·P^T (16x16x16 f16): P^T B-frag == S^T C-layout in-lane.
// Q pre-scaled by 0.125*log2e -> softmax in exp2 domain.
// ---------------------------------------------------------------------------
__global__ __launch_bounds__(256, 4)
void attn_fwd(const _Float16* __restrict__ Q, const _Float16* __restrict__ K,
              const _Float16* __restrict__ Vt, u16* __restrict__ O)
{
  const int bh   = blockIdx.y;
  const int r0   = ((int)gridDim.x - 1 - (int)blockIdx.x) * 128;  // heavy first
  const int t    = threadIdx.x;
  const int w    = t >> 6, lane = t & 63;
  const int quad = lane >> 4, l15 = lane & 15;
  const int qb   = r0 + w * 32;

  half8_t qf[2][2];
  {
    const _Float16* Qp = Q + ((size_t)bh * SEQ + qb + l15) * DK + quad * 8;
#pragma unroll
    for (int qs = 0; qs < 2; ++qs)
#pragma unroll
      for (int ks = 0; ks < 2; ++ks)
        qf[qs][ks] = *(const half8_t*)(Qp + qs * 16 * DK + ks * 32);
  }

  const _Float16* Kb = K  + (size_t)bh * SEQ * DK;   // [key][d]
  const _Float16* Vb = Vt + (size_t)bh * DK * SEQ;   // [d][key]

  float mrow[2]  = { -1e30f, -1e30f };
  float lpart[2] = { 0.f, 0.f };
  floatx4 o[2][4] = {};

  const int jend = qb + 32;
  for (int j0 = 0; j0 < jend; j0 += 64) {
    // ---- phase 1: S^T tiles; K-frags straight from global (row-coalesced)
    half8_t ka[4][2];
#pragma unroll
    for (int kt = 0; kt < 4; ++kt) {
      const _Float16* kp = Kb + (size_t)(j0 + kt*16 + l15) * DK + quad*8;
      ka[kt][0] = *(const half8_t*)kp;
      ka[kt][1] = *(const half8_t*)(kp + 32);
    }
    floatx4 st[2][4];
#pragma unroll
    for (int kt = 0; kt < 4; ++kt) {
      floatx4 s0 = {}, s1 = {};
      s0 = __builtin_amdgcn_mfma_f32_16x16x32_f16(ka[kt][0], qf[0][0], s0, 0, 0, 0);
      s0 = __builtin_amdgcn_mfma_f32_16x16x32_f16(ka[kt][1], qf[0][1], s0, 0, 0, 0);
      s1 = __builtin_amdgcn_mfma_f32_16x16x32_f16(ka[kt][0], qf[1][0], s1, 0, 0, 0);
      s1 = __builtin_amdgcn_mfma_f32_16x16x32_f16(ka[kt][1], qf[1][1], s1, 0, 0, 0);
      st[0][kt] = s0; st[1][kt] = s1;
    }

    // ---- prefetch V^T-frags (independent of softmax chain)
    half4_t vf[4][4];
#pragma unroll
    for (int dt = 0; dt < 4; ++dt) {
      const _Float16* vp = Vb + (size_t)(dt*16 + l15) * SEQ + j0 + quad*4;
#pragma unroll
      for (int kt = 0; kt < 4; ++kt)
        vf[dt][kt] = *(const half4_t*)(vp + kt*16);
    }

    // ---- mask (diagonal tile only) + online softmax (exp2 domain)
    half4_t pf[2][4];
#pragma unroll
    for (int qs = 0; qs < 2; ++qs) {
      const int qlo = qb + qs * 16;
      if (j0 + 63 > qlo) {                       // wave-uniform branch
        const int query = qlo + l15;
#pragma unroll
        for (int kt = 0; kt < 4; ++kt)
#pragma unroll
          for (int r = 0; r < 4; ++r)
            if (j0 + kt*16 + quad*4 + r > query) st[qs][kt][r] = -1e30f;
      }
      float m0v = -1e30f;
#pragma unroll
      for (int kt = 0; kt < 4; ++kt)
        m0v = fmaxf(m0v, fmaxf(fmaxf(st[qs][kt][0], st[qs][kt][1]),
                               fmaxf(st[qs][kt][2], st[qs][kt][3])));
      m0v = fmaxf(m0v, __shfl_xor(m0v, 16));
      m0v = fmaxf(m0v, __shfl_xor(m0v, 32));
      const float mn    = fmaxf(mrow[qs], m0v);
      const float alpha = exp2f(mrow[qs] - mn);  // 0 on first tile
      mrow[qs] = mn;
      lpart[qs] *= alpha;
#pragma unroll
      for (int kt = 0; kt < 4; ++kt) {
        const float p0 = exp2f(st[qs][kt][0] - mn), p1 = exp2f(st[qs][kt][1] - mn);
        const float p2 = exp2f(st[qs][kt][2] - mn), p3 = exp2f(st[qs][kt][3] - mn);
        lpart[qs] += (p0 + p1) + (p2 + p3);
        union { half4_t h; uint2 u; } pc;
        pc.u = make_uint2(pkh(p0, p1), pkh(p2, p3));
        pf[qs][kt] = pc.h;
      }
#pragma unroll
      for (int dt = 0; dt < 4; ++dt) {
        o[qs][dt][0] *= alpha; o[qs][dt][1] *= alpha;
        o[qs][dt][2] *= alpha; o[qs][dt][3] *= alpha;
      }
    }

    // ---- phase 2: O^T += V^T · P^T
#pragma unroll
    for (int dt = 0; dt < 4; ++dt)
#pragma unroll
      for (int kt = 0; kt < 4; ++kt) {
        o[0][dt] = __builtin_amdgcn_mfma_f32_16x16x16f16(vf[dt][kt], pf[0][kt], o[0][dt], 0, 0, 0);
        o[1][dt] = __builtin_amdgcn_mfma_f32_16x16x16f16(vf[dt][kt], pf[1][kt], o[1][dt], 0, 0, 0);
      }
  }

  // ---- epilogue: deferred l reduction, O bf16 [B,S,D]
  const int b = bh >> 4, h = bh & 15;
#pragma unroll
  for (int qs = 0; qs < 2; ++qs) {
    float l = lpart[qs];
    l += __shfl_xor(l, 16);
    l += __shfl_xor(l, 32);
    const float inv = 1.0f / l;
    const int query = qb + qs*16 + l15;
    u16* Op = O + ((size_t)(b * SEQ + query)) * D_MODEL + h * DK + quad * 4;
#pragma unroll
    for (int dt = 0; dt < 4; ++dt) {
      u32 lo = ((u32)f2bf(o[qs][dt][1] * inv) << 16) | f2bf(o[qs][dt][0] * inv);
      u32 hi = ((u32)f2bf(o[qs][dt][3] * inv) << 16) | f2bf(o[qs][dt][2] * inv);
      *(uint2*)(Op + dt * 16) = make_uint2(lo, hi);
    }
  }
}

// ---------------------------------------------------------------------------
extern "C" void kernel_launch(void* const* d_in, const int* in_sizes, int n_in,
                              void* d_out, int out_size, void* d_ws, size_t ws_size,
                              hipStream_t stream)
{
  const float* x  = (const float*)d_in[0];
  const float* Wq = (const float*)d_in[1];
  const float* bq = (const float*)d_in[2];
  const float* Wk = (const float*)d_in[3];
  const float* bk = (const float*)d_in[4];
  const float* Wv = (const float*)d_in[5];
  const float* bv = (const float*)d_in[6];
  const float* Wo = (const float*)d_in[7];
  const float* bo = (const float*)d_in[8];

  const size_t tsz = (size_t)MTOT * D_MODEL;   // 8,388,608
  const size_t wsz = (size_t)D_MODEL * D_MODEL;

  const dim3 gg(D_MODEL/128, MTOT/128);        // 8 x 64 = 512 blocks
  const dim3 ga(SEQ/128, BATCH*NHEAD);         // 16 x 64 = 1024 blocks
  const float qscale = 0.18033688f;            // 1/sqrt(64) * log2(e)

  if (ws_size >= 2 * (4*tsz + 4*wsz)) {        // 75.5 MB: bf16 fast path
    u16* xb  = (u16*)d_ws;
    u16* wqb = xb + tsz;
    u16* wkb = wqb + wsz;
    u16* wvb = wkb + wsz;
    u16* wob = wvb + wsz;
    u16* Qw  = wob + wsz;
    u16* Kw  = Qw + tsz;
    u16* Vtw = Kw + tsz;
    u16* Ow  = xb;                             // xb dead after QKV GEMMs

    cvt_bf16<<<4096 + 4*512, 256, 0, stream>>>(x, Wq, Wk, Wv, Wo,
                                               xb, wqb, wkb, wvb, wob);
    gemm_bt<1,1,1><<<gg, 256, 0, stream>>>(xb, wqb, bq, Qw,  qscale);
    gemm_bt<1,1,1><<<gg, 256, 0, stream>>>(xb, wkb, bk, Kw,  1.0f);
    gemm_bt<2,1,1><<<gg, 256, 0, stream>>>(xb, wvb, bv, Vtw, 1.0f);
    attn_fwd<<<ga, 256, 0, stream>>>(
        (const _Float16*)Qw, (const _Float16*)Kw, (const _Float16*)Vtw, Ow);
    gemm_bt<0,1,1><<<gg, 256, 0, stream>>>(Ow, wob, bo, d_out, 1.0f);
  } else {                                     // 67.1 MB fallback
    u16* Qw  = (u16*)d_ws;
    u16* Kw  = Qw + tsz;
    u16* Vtw = Kw + tsz;
    u16* Ow  = Vtw + tsz;

    gemm_bt<1,0,0><<<gg, 256, 0, stream>>>(x, Wq, bq, Qw,  qscale);
    gemm_bt<1,0,0><<<gg, 256, 0, stream>>>(x, Wk, bk, Kw,  1.0f);
    gemm_bt<2,0,0><<<gg, 256, 0, stream>>>(x, Wv, bv, Vtw, 1.0f);
    attn_fwd<<<ga, 256, 0, stream>>>(
        (const _Float16*)Qw, (const _Float16*)Kw, (const _Float16*)Vtw, Ow);
    gemm_bt<0,1,0><<<gg, 256, 0, stream>>>(Ow, Wo, bo, d_out, 1.0f);
  }
}